// Round 19
// baseline (401.178 us; speedup 1.0000x reference)
//
#include <hip/hip_runtime.h>

typedef unsigned long long u64;

#define WIDTH   800
#define HEIGHT  600
#define HWPX    (WIDTH*HEIGHT)
#define RAD     3
#define TILE    8
#define TXN     100         // 800/8
#define TYN     75          // 600/8
#define NTILES  (TXN*TYN)   // 7500
#define KSUB    4           // sub-lists per tile
#define SUBCAP  96          // slots per sub-list
#define TCAP    (KSUB*SUBCAP) // 384 storage slots per tile
#define RCAP    256         // render handles <= 256 entries
#define REGION  (NTILES*KSUB*16)   // ints per counter region (padded)

// self-contained 32B bin entry
struct alignas(16) Entry {
    u64   key;              // (~depth_bits)<<32 | idx  (depth desc, idx asc)
    int   xy;               // xi | yi<<16
    float op;
    float r, g, b;
    float pad;
};

// ---------------- shared helpers ----------------
__device__ __forceinline__ void make_tinv(const float* __restrict__ ext, double* tinv) {
    if (threadIdx.x == 0) {
        double A[4][8];
        for (int i = 0; i < 4; ++i)
            for (int j = 0; j < 4; ++j) { A[i][j] = (double)ext[i*4+j]; A[i][j+4] = (i == j) ? 1.0 : 0.0; }
        for (int c = 0; c < 4; ++c) {
            int p = c; double mx = fabs(A[c][c]);
            for (int r = c+1; r < 4; ++r) { double v = fabs(A[r][c]); if (v > mx) { mx = v; p = r; } }
            if (p != c) for (int j = 0; j < 8; ++j) { double t = A[c][j]; A[c][j] = A[p][j]; A[p][j] = t; }
            double piv = A[c][c];
            for (int j = 0; j < 8; ++j) A[c][j] /= piv;
            for (int r = 0; r < 4; ++r) {
                if (r == c) continue;
                double f = A[r][c];
                for (int j = 0; j < 8; ++j) A[r][j] -= f * A[c][j];
            }
        }
        for (int i = 0; i < 4; ++i)
            for (int j = 0; j < 4; ++j) tinv[i*4+j] = A[i][j+4];
    }
    __syncthreads();
}

// mode: 0 = full, 1 = atomics but no entry stores, 2 = math+loads only
__device__ __forceinline__ void project_point(int i, int N,
        const float* __restrict__ xyz, const float* __restrict__ opacity,
        const float* __restrict__ features, const float* __restrict__ K,
        const double* tinv, int* __restrict__ counters,
        Entry* __restrict__ entries, int mode) {
    if (i >= N) return;
    float op = opacity[i];
    float fr = features[i*48+0], fg = features[i*48+1], fb = features[i*48+2];

    double x = (double)xyz[3*i], y = (double)xyz[3*i+1], z = (double)xyz[3*i+2];
    double cam[3];
#pragma unroll
    for (int j = 0; j < 3; ++j)
        cam[j] = x*tinv[4*j+0] + y*tinv[4*j+1] + z*tinv[4*j+2] + tinv[4*j+3];
    double s0 = cam[0]*(double)K[0] + cam[1]*(double)K[1] + cam[2]*(double)K[2];
    double s1 = cam[0]*(double)K[3] + cam[1]*(double)K[4] + cam[2]*(double)K[5];
    double s2 = cam[0]*(double)K[6] + cam[1]*(double)K[7] + cam[2]*(double)K[8];
    double px = s0 / s2, py = s1 / s2;
    double dep = cam[2];
    bool valid = (px >= 0.0) && (px < (double)WIDTH) && (py >= 0.0) && (py < (double)HEIGHT) && (dep > 0.0);
    if (!valid) return;
    int xi = (int)px, yi = (int)py;

    unsigned db = __float_as_uint((float)dep);
    Entry e;
    e.key = ((u64)(~db) << 32) | (unsigned)i;
    e.xy  = xi | (yi << 16);
    e.op  = op;
    e.r = fr; e.g = fg; e.b = fb;
    e.pad = 0.f;

    if (mode == 2) {   // keep results live without side effects (rule #17)
        asm volatile("" :: "v"(e.xy), "v"(e.op), "v"(e.r),
                          "v"((int)(e.key & 0xFFFFFFFFull)), "v"((int)(e.key >> 32)));
        return;
    }

    int sub = i & (KSUB - 1);
    int x0t = max(xi-RAD, 0) >> 3, x1t = min(xi+RAD, WIDTH-1)  >> 3;
    int y0t = max(yi-RAD, 0) >> 3, y1t = min(yi+RAD, HEIGHT-1) >> 3;
    bool hx = (x1t != x0t), hy = (y1t != y0t);
    int t00 = y0t*TXN + x0t;
    int t01 = t00 + 1;
    int t10 = t00 + TXN;
    int t11 = t10 + 1;

    int p00 = atomicAdd(&counters[(t00*KSUB + sub) << 4], 1);
    int p01 = hx        ? atomicAdd(&counters[(t01*KSUB + sub) << 4], 1) : SUBCAP;
    int p10 = hy        ? atomicAdd(&counters[(t10*KSUB + sub) << 4], 1) : SUBCAP;
    int p11 = (hx && hy)? atomicAdd(&counters[(t11*KSUB + sub) << 4], 1) : SUBCAP;

    if (mode == 1) return;

    size_t sb = (size_t)sub * SUBCAP;
    if (p00 < SUBCAP) entries[(size_t)t00*TCAP + sb + p00] = e;
    if (p01 < SUBCAP) entries[(size_t)t01*TCAP + sb + p01] = e;
    if (p10 < SUBCAP) entries[(size_t)t10*TCAP + sb + p10] = e;
    if (p11 < SUBCAP) entries[(size_t)t11*TCAP + sb + p11] = e;
}

// ---------------- render body (shared by real kernel and probe) ----------------
struct RenderShared {
    alignas(16) u64 kbuf[RCAP];
    u64    mask[RCAP];
    float  w[49];
    int2   eop[RCAP];
    float4 rgbd[RCAP];
    float4 r_c[256];
    float2 r_ad[256];
};

__device__ __forceinline__ void render_tile(RenderShared& S, int tile,
        const int* __restrict__ tileCount, const Entry* __restrict__ entries,
        float* __restrict__ out) {
    int tid  = threadIdx.x;
    int lane = tid & 63, wid = tid >> 6;
    size_t start = (size_t)tile * TCAP;
    int tx0 = (tile % TXN) * TILE;
    int ty0 = (tile / TXN) * TILE;

    int c0 = min(tileCount[(tile*KSUB + 0) << 4], SUBCAP);
    int c1 = min(tileCount[(tile*KSUB + 1) << 4], SUBCAP);
    int c2 = min(tileCount[(tile*KSUB + 2) << 4], SUBCAP);
    int c3 = min(tileCount[(tile*KSUB + 3) << 4], SUBCAP);
    int o1 = c0, o2 = c0 + c1, o3 = c0 + c1 + c2;
    int cnt = o3 + c3;
    if (cnt > RCAP) cnt = RCAP;

    if (tid < 49) {
        int dx = tid % 7 - 3, dy = tid / 7 - 3;
        S.w[tid] = (float)exp(-0.5 * (double)(dx*dx + dy*dy));
    }

    u64 key = ~0ull;
    Entry e;
    float dep = 0.f;
    if (tid < cnt) {
        int s, pos;
        if (tid < o1)      { s = 0; pos = tid; }
        else if (tid < o2) { s = 1; pos = tid - o1; }
        else if (tid < o3) { s = 2; pos = tid - o2; }
        else               { s = 3; pos = tid - o3; }
        e = entries[start + (size_t)s * SUBCAP + pos];
        key = e.key;
        dep = __uint_as_float(~(unsigned)(key >> 32));
    }
    S.kbuf[tid] = key;
    __syncthreads();

    if (tid < cnt) {
        int rank = 0;
        int cr2 = (cnt + 1) & ~1;
        const ulonglong2* kb2 = (const ulonglong2*)S.kbuf;
        for (int j = 0; j < cr2; j += 2) {
            ulonglong2 kk = kb2[j >> 1];
            rank += (kk.x < key) + (kk.y < key);
        }
        int dxc = (e.xy & 0xFFFF) - tx0;
        int dyc = (e.xy >> 16)    - ty0;
        int sx = dxc - 3, sy = dyc - 3;
        unsigned rm = (sx >= 0) ? ((0x7Fu << sx) & 0xFFu) : (0x7Fu >> (-sx));
        unsigned ym = (sy >= 0) ? ((0x7Fu << sy) & 0xFFu) : (0x7Fu >> (-sy));
        u64 msk = 0;
#pragma unroll
        for (int r = 0; r < 8; ++r)
            msk |= (u64)((ym >> r) & 1u ? rm : 0u) << (8 * r);
        S.mask[rank] = msk;
        S.eop[rank]  = make_int2((3 - dyc) * 7 + (3 - dxc), __float_as_int(e.op));
        S.rgbd[rank] = make_float4(e.r, e.g, e.b, dep);
    }
    __syncthreads();

    int seg = (cnt + 3) >> 2;
    int sA = wid * seg, sB = min(sA + seg, cnt);
    int m = sB - sA; if (m < 0) m = 0;
    int laneterm = (lane >> 3) * 7 + (lane & 7);

    float T = 1.f, Sr = 0.f, Sg = 0.f, Sb = 0.f, Aa = 0.f, Dm = 0.f;
    for (int k2 = 0; k2 < m; ++k2) {
        int q = sA + k2;
        u64 msk = S.mask[q];
        if ((msk >> lane) & 1ull) {
            int2 eo = S.eop[q];
            float4 cd = S.rgbd[q];
            float w  = S.w[laneterm + eo.x];
            float a  = __int_as_float(eo.y) * w;
            float ia = 1.f - a;
            Sr = Sr * ia + cd.x * a;
            Sg = Sg * ia + cd.y * a;
            Sb = Sb * ia + cd.z * a;
            T *= ia;
            Aa = Aa + a * (1.f - Aa);
            float d = cd.w;
            Dm = (Dm == 0.f || d < Dm) ? d : Dm;
        }
    }

    S.r_c[tid]  = make_float4(T, Sr, Sg, Sb);
    S.r_ad[tid] = make_float2(Aa, Dm);
    __syncthreads();

    if (wid == 0) {
        float cr = 0.f, cg = 0.f, cb = 0.f, al = 0.f, dm = 0.f;
#pragma unroll
        for (int w = 0; w < 4; ++w) {
            int q = w * 64 + lane;
            float4 c = S.r_c[q];
            float2 ad = S.r_ad[q];
            cr = cr * c.x + c.y;
            cg = cg * c.x + c.z;
            cb = cb * c.x + c.w;
            al = al + ad.x * (1.f - al);
            float d = ad.y;
            if (d != 0.f && (dm == 0.f || d < dm)) dm = d;
        }
        int px = tx0 + (lane & 7);
        int py = ty0 + (lane >> 3);
        int pix = py * WIDTH + px;
        out[pix]          = cr;
        out[HWPX + pix]   = cg;
        out[2*HWPX + pix] = cb;
        out[3*HWPX + pix] = dm;
        out[4*HWPX + pix] = al;
    }
    __syncthreads();
}

// ---------------- real kernels (byte-equivalent behavior to r18) ----------------
__global__ void project_bin_kernel(const float* __restrict__ xyz,
                                   const float* __restrict__ opacity,
                                   const float* __restrict__ features,
                                   const float* __restrict__ K,
                                   const float* __restrict__ ext,
                                   int* __restrict__ tileCount,
                                   Entry* __restrict__ entries, int N) {
    __shared__ double tinv[16];
    make_tinv(ext, tinv);
    int i = blockIdx.x * blockDim.x + threadIdx.x;
    project_point(i, N, xyz, opacity, features, K, tinv, tileCount, entries, 0);
}

__global__ __launch_bounds__(256, 8) void render_kernel(
        const int* __restrict__ tileCount,
        const Entry* __restrict__ entries,
        float* __restrict__ out) {
    __shared__ RenderShared S;
    render_tile(S, blockIdx.x, tileCount, entries, out);
}

// ---------------- probes (measurement only; outputs go to ws) ----------------
__global__ void probe_project(const float* __restrict__ xyz,
                              const float* __restrict__ opacity,
                              const float* __restrict__ features,
                              const float* __restrict__ K,
                              const float* __restrict__ ext,
                              int* __restrict__ probeCnt,
                              Entry* __restrict__ entries, int N,
                              int reps, int mode) {
    __shared__ double tinv[16];
    make_tinv(ext, tinv);
    int i = blockIdx.x * blockDim.x + threadIdx.x;
    for (int r = 0; r < reps; ++r)
        project_point(i, N, xyz, opacity, features, K, tinv,
                      probeCnt + (size_t)(r & 3) * REGION, entries, mode);
}

__global__ __launch_bounds__(256, 8) void probe_render(
        const int* __restrict__ tileCount,
        const Entry* __restrict__ entries,
        float* __restrict__ dummy, int reps) {
    __shared__ RenderShared S;
    for (int r = 0; r < reps; ++r)
        render_tile(S, blockIdx.x, tileCount, entries, dummy);
}

// ---------------- host launch ----------------
extern "C" void kernel_launch(void* const* d_in, const int* in_sizes, int n_in,
                              void* d_out, int out_size, void* d_ws, size_t ws_size,
                              hipStream_t stream) {
    const float* xyz      = (const float*)d_in[0];
    const float* opacity  = (const float*)d_in[3];
    const float* features = (const float*)d_in[4];
    const float* K        = (const float*)d_in[5];
    const float* ext      = (const float*)d_in[6];
    int N = in_sizes[0] / 3;

    char* ws = (char*)d_ws;
    size_t off = 0;
    int* tileCount = (int*)(ws + off);   off += (size_t)REGION * sizeof(int);        // 1.92 MB
    int* probeCnt  = (int*)(ws + off);   off += (size_t)4 * REGION * sizeof(int);    // 7.68 MB
    size_t zeroBytes = off;                                                           // 9.6 MB zeroed
    off = (off + 127) & ~(size_t)127;
    float* dummyOut = (float*)(ws + off); off += (size_t)5 * HWPX * sizeof(float);   // 9.6 MB
    off = (off + 127) & ~(size_t)127;
    Entry* entries = (Entry*)(ws + off);  off += (size_t)NTILES * TCAP * sizeof(Entry); // 92.2 MB

    hipMemsetAsync(ws, 0, zeroBytes, stream);
    int blocks = (N + 255) / 256;

    // real pipeline (identical to the 57.6 us configuration)
    project_bin_kernel<<<blocks, 256, 0, stream>>>(xyz, opacity, features, K, ext,
                                                   tileCount, entries, N);
    render_kernel<<<NTILES, 256, 0, stream>>>(tileCount, entries, (float*)d_out);

    // measurement probes (trash entries AFTER the real render; d_out untouched)
    probe_project<<<blocks, 256, 0, stream>>>(xyz, opacity, features, K, ext,
                                              probeCnt, entries, N, 4, 0);   // ~4x full P
    probe_project<<<blocks, 256, 0, stream>>>(xyz, opacity, features, K, ext,
                                              probeCnt, entries, N, 12, 1);  // ~12x no-store P
    probe_project<<<blocks, 256, 0, stream>>>(xyz, opacity, features, K, ext,
                                              probeCnt, entries, N, 48, 2);  // ~48x math+loads P
    probe_render<<<NTILES, 256, 0, stream>>>(tileCount, entries, dummyOut, 4); // ~4x warm R
}

// Round 20
// 58.131 us; speedup vs baseline: 6.9013x; 6.9013x over previous
//
#include <hip/hip_runtime.h>

typedef unsigned long long u64;

#define WIDTH   800
#define HEIGHT  600
#define HWPX    (WIDTH*HEIGHT)
#define RAD     3
#define TILE    8
#define TXN     100         // 800/8
#define TYN     75          // 600/8
#define NTILES  (TXN*TYN)   // 7500
#define KSUB    4           // sub-lists per tile
#define SUBCAP  96          // slots per sub-list
#define TCAP    (KSUB*SUBCAP) // 384 storage slots per tile
#define RCAP    256         // render handles <= 256 entries (empirical max ~230)

// contiguous per-point payload (written coalesced once; gathered in render)
struct alignas(16) PD { int xy; float op, r, g; float b; int pad[3]; };  // 32B

// ---- fused: f64 extrinsics-inverse + projection + split-K key-only binning ----
__global__ void project_bin_kernel(const float* __restrict__ xyz,
                                   const float* __restrict__ opacity,
                                   const float* __restrict__ features,
                                   const float* __restrict__ K,
                                   const float* __restrict__ ext,
                                   int* __restrict__ tileCount,
                                   u64* __restrict__ keys,
                                   PD* __restrict__ pd, int N) {
    __shared__ double tinv[16];
    if (threadIdx.x == 0) {
        double A[4][8];
        for (int i = 0; i < 4; ++i)
            for (int j = 0; j < 4; ++j) { A[i][j] = (double)ext[i*4+j]; A[i][j+4] = (i == j) ? 1.0 : 0.0; }
        for (int c = 0; c < 4; ++c) {
            int p = c; double mx = fabs(A[c][c]);
            for (int r = c+1; r < 4; ++r) { double v = fabs(A[r][c]); if (v > mx) { mx = v; p = r; } }
            if (p != c) for (int j = 0; j < 8; ++j) { double t = A[c][j]; A[c][j] = A[p][j]; A[p][j] = t; }
            double piv = A[c][c];
            for (int j = 0; j < 8; ++j) A[c][j] /= piv;
            for (int r = 0; r < 4; ++r) {
                if (r == c) continue;
                double f = A[r][c];
                for (int j = 0; j < 8; ++j) A[r][j] -= f * A[c][j];
            }
        }
        for (int i = 0; i < 4; ++i)
            for (int j = 0; j < 4; ++j) tinv[i*4+j] = A[i][j+4];
    }
    __syncthreads();

    int i = blockIdx.x * blockDim.x + threadIdx.x;
    if (i >= N) return;

    // hoisted loads: depend only on i, overlap the f64 chain below
    float op = opacity[i];
    float fr = features[i*48+0], fg = features[i*48+1], fb = features[i*48+2];

    double x = (double)xyz[3*i], y = (double)xyz[3*i+1], z = (double)xyz[3*i+2];
    double cam[3];
#pragma unroll
    for (int j = 0; j < 3; ++j)
        cam[j] = x*tinv[4*j+0] + y*tinv[4*j+1] + z*tinv[4*j+2] + tinv[4*j+3];
    double s0 = cam[0]*(double)K[0] + cam[1]*(double)K[1] + cam[2]*(double)K[2];
    double s1 = cam[0]*(double)K[3] + cam[1]*(double)K[4] + cam[2]*(double)K[5];
    double s2 = cam[0]*(double)K[6] + cam[1]*(double)K[7] + cam[2]*(double)K[8];
    double px = s0 / s2, py = s1 / s2;
    double dep = cam[2];
    bool valid = (px >= 0.0) && (px < (double)WIDTH) && (py >= 0.0) && (py < (double)HEIGHT) && (dep > 0.0);
    if (!valid) return;                         // invalid points are never referenced
    int xi = (int)px, yi = (int)py;             // trunc == floor for px,py >= 0

    PD p;
    p.xy = xi | (yi << 16);
    p.op = op; p.r = fr; p.g = fg; p.b = fb;
    p.pad[0] = p.pad[1] = p.pad[2] = 0;
    pd[i] = p;                                  // contiguous 32B store (coalesced)

    unsigned db = __float_as_uint((float)dep);  // depth > 0 -> bits monotonic
    u64 key = ((u64)(~db) << 32) | (unsigned)i; // depth desc, idx asc (stable ref order)

    int sub = i & (KSUB - 1);                   // writers of a tile spread uniformly over subs

    // straight-line the <=4 tile updates: independent atomics, then stores
    int x0t = max(xi-RAD, 0) >> 3, x1t = min(xi+RAD, WIDTH-1)  >> 3;
    int y0t = max(yi-RAD, 0) >> 3, y1t = min(yi+RAD, HEIGHT-1) >> 3;
    bool hx = (x1t != x0t), hy = (y1t != y0t);
    int t00 = y0t*TXN + x0t;
    int t01 = t00 + 1;                 // valid iff hx
    int t10 = t00 + TXN;               // valid iff hy
    int t11 = t10 + 1;                 // valid iff hx && hy

    // counter index: (tile*KSUB + sub) * 16 ints -> one counter per 64B line
    int p00 = atomicAdd(&tileCount[(t00*KSUB + sub) << 4], 1);
    int p01 = hx        ? atomicAdd(&tileCount[(t01*KSUB + sub) << 4], 1) : SUBCAP;
    int p10 = hy        ? atomicAdd(&tileCount[(t10*KSUB + sub) << 4], 1) : SUBCAP;
    int p11 = (hx && hy)? atomicAdd(&tileCount[(t11*KSUB + sub) << 4], 1) : SUBCAP;

    size_t sb = (size_t)sub * SUBCAP;
    if (p00 < SUBCAP) keys[(size_t)t00*TCAP + sb + p00] = key;   // 8B scatter
    if (p01 < SUBCAP) keys[(size_t)t01*TCAP + sb + p01] = key;
    if (p10 < SUBCAP) keys[(size_t)t10*TCAP + sb + p10] = key;
    if (p11 < SUBCAP) keys[(size_t)t11*TCAP + sb + p11] = key;
}

// ---- render: 256 threads (4 waves) per 8x8 tile; rank sort + mask-driven segmented blend ----
__global__ __launch_bounds__(256, 8) void render_kernel(
        const int* __restrict__ tileCount,
        const u64* __restrict__ keys,
        const PD* __restrict__ pd,
        float* __restrict__ out) {
    __shared__ alignas(16) u64 kbuf[RCAP];
    __shared__ u64    s_mask[RCAP];    // 64-bit pixel coverage mask per entry
    __shared__ float  s_w[49];
    __shared__ int2   s_eop[RCAP];     // .x = eterm (weight-index base), .y = op bits
    __shared__ float4 s_rgbd[RCAP];    // r,g,b,depth
    __shared__ float4 r_c[256];        // T,Sr,Sg,Sb
    __shared__ float2 r_ad[256];       // A,D

    int tile = blockIdx.x;
    int tid  = threadIdx.x;
    int lane = tid & 63, wid = tid >> 6;
    size_t start = (size_t)tile * TCAP;
    int tx0 = (tile % TXN) * TILE;
    int ty0 = (tile / TXN) * TILE;

    // gather the 4 sub-counts; cnt = total (clamped to what we can sort)
    int c0 = min(tileCount[(tile*KSUB + 0) << 4], SUBCAP);
    int c1 = min(tileCount[(tile*KSUB + 1) << 4], SUBCAP);
    int c2 = min(tileCount[(tile*KSUB + 2) << 4], SUBCAP);
    int c3 = min(tileCount[(tile*KSUB + 3) << 4], SUBCAP);
    int o1 = c0, o2 = c0 + c1, o3 = c0 + c1 + c2;
    int cnt = o3 + c3;
    if (cnt > RCAP) cnt = RCAP;

    if (tid < 49) {
        int dx = tid % 7 - 3, dy = tid / 7 - 3;
        s_w[tid] = (float)exp(-0.5 * (double)(dx*dx + dy*dy));
    }

    // one entry per thread: coalesced 8B key load + early pd gather (overlaps rank loop)
    u64 key = ~0ull;
    PD p;
    float dep = 0.f;
    if (tid < cnt) {
        int s, pos;
        if (tid < o1)      { s = 0; pos = tid; }
        else if (tid < o2) { s = 1; pos = tid - o1; }
        else if (tid < o3) { s = 2; pos = tid - o2; }
        else               { s = 3; pos = tid - o3; }
        key = keys[start + (size_t)s * SUBCAP + pos];
        p = pd[(unsigned)(key & 0xFFFFFFFFull)];   // gather issued here, used after rank loop
        dep = __uint_as_float(~(unsigned)(key >> 32));
    }
    kbuf[tid] = key;                   // slots >= cnt hold ~0 (pad, never < key)
    __syncthreads();

    if (tid < cnt) {
        int rank = 0;
        int cr2 = (cnt + 1) & ~1;      // pad slot makes the pair read exact
        const ulonglong2* kb2 = (const ulonglong2*)kbuf;
        for (int j = 0; j < cr2; j += 2) {         // b128 broadcast: 2 keys/read
            ulonglong2 kk = kb2[j >> 1];
            rank += (kk.x < key) + (kk.y < key);
        }
        // coverage mask + additive weight-index term (computed once per entry)
        int dxc = (p.xy & 0xFFFF) - tx0;           // splat center rel. tile, in [-3, 10]
        int dyc = (p.xy >> 16)    - ty0;
        int sx = dxc - 3, sy = dyc - 3;
        unsigned rm = (sx >= 0) ? ((0x7Fu << sx) & 0xFFu) : (0x7Fu >> (-sx));
        unsigned ym = (sy >= 0) ? ((0x7Fu << sy) & 0xFFu) : (0x7Fu >> (-sy));
        u64 msk = 0;
#pragma unroll
        for (int r = 0; r < 8; ++r)
            msk |= (u64)((ym >> r) & 1u ? rm : 0u) << (8 * r);
        s_mask[rank] = msk;
        s_eop[rank]  = make_int2((3 - dyc) * 7 + (3 - dxc), __float_as_int(p.op));
        s_rgbd[rank] = make_float4(p.r, p.g, p.b, dep);
    }
    __syncthreads();

    // each wave blends one contiguous depth segment (over-op is associative)
    int seg = (cnt + 3) >> 2;           // <= 64 since cnt <= 256
    int sA = wid * seg, sB = min(sA + seg, cnt);
    int m = sB - sA; if (m < 0) m = 0;
    int laneterm = (lane >> 3) * 7 + (lane & 7);   // widx = laneterm + eterm, in [0,48] when covered

    float T = 1.f, Sr = 0.f, Sg = 0.f, Sb = 0.f, Aa = 0.f, Dm = 0.f;
    for (int k2 = 0; k2 < m; ++k2) {
        int q = sA + k2;
        u64 msk = s_mask[q];                        // broadcast read
        if ((msk >> lane) & 1ull) {
            int2 eo = s_eop[q];
            float4 cd = s_rgbd[q];
            float w  = s_w[laneterm + eo.x];
            float a  = __int_as_float(eo.y) * w;
            float ia = 1.f - a;
            Sr = Sr * ia + cd.x * a;
            Sg = Sg * ia + cd.y * a;
            Sb = Sb * ia + cd.z * a;
            T *= ia;
            Aa = Aa + a * (1.f - Aa);
            float d = cd.w;
            Dm = (Dm == 0.f || d < Dm) ? d : Dm;
        }
    }

    r_c[tid]  = make_float4(T, Sr, Sg, Sb);
    r_ad[tid] = make_float2(Aa, Dm);
    __syncthreads();

    if (wid == 0) {   // compose 4 segments farthest->nearest, write all 5 planes
        float cr = 0.f, cg = 0.f, cb = 0.f, al = 0.f, dm = 0.f;
#pragma unroll
        for (int w = 0; w < 4; ++w) {
            int q = w * 64 + lane;
            float4 c = r_c[q];
            float2 ad = r_ad[q];
            cr = cr * c.x + c.y;
            cg = cg * c.x + c.z;
            cb = cb * c.x + c.w;
            al = al + ad.x * (1.f - al);
            float d = ad.y;
            if (d != 0.f && (dm == 0.f || d < dm)) dm = d;
        }
        int px = tx0 + (lane & 7);
        int py = ty0 + (lane >> 3);
        int pix = py * WIDTH + px;
        out[pix]          = cr;
        out[HWPX + pix]   = cg;
        out[2*HWPX + pix] = cb;
        out[3*HWPX + pix] = dm;
        out[4*HWPX + pix] = al;
    }
}

// ---------------- host launch ----------------
extern "C" void kernel_launch(void* const* d_in, const int* in_sizes, int n_in,
                              void* d_out, int out_size, void* d_ws, size_t ws_size,
                              hipStream_t stream) {
    const float* xyz      = (const float*)d_in[0];
    const float* opacity  = (const float*)d_in[3];
    const float* features = (const float*)d_in[4];
    const float* K        = (const float*)d_in[5];
    const float* ext      = (const float*)d_in[6];
    int N = in_sizes[0] / 3;

    char* ws = (char*)d_ws;
    size_t off = 0;
    int* tileCount = (int*)(ws + off);
    off += (size_t)NTILES * KSUB * 16 * sizeof(int);   // 1.92 MB: one counter per 64B line
    off = (off + 127) & ~(size_t)127;
    PD* pd = (PD*)(ws + off);
    off += (size_t)N * sizeof(PD);                     // 3.2 MB contiguous payload
    off = (off + 127) & ~(size_t)127;
    u64* keys = (u64*)(ws + off);
    off += (size_t)NTILES * TCAP * sizeof(u64);        // 23 MB key slots

    hipMemsetAsync(tileCount, 0, (size_t)NTILES * KSUB * 16 * sizeof(int), stream);
    int blocks = (N + 255) / 256;
    project_bin_kernel<<<blocks, 256, 0, stream>>>(xyz, opacity, features, K, ext,
                                                   tileCount, keys, pd, N);
    render_kernel<<<NTILES, 256, 0, stream>>>(tileCount, keys, pd, (float*)d_out);
}

// Round 21
// 56.637 us; speedup vs baseline: 7.0833x; 1.0264x over previous
//
#include <hip/hip_runtime.h>

typedef unsigned long long u64;

#define WIDTH   800
#define HEIGHT  600
#define HWPX    (WIDTH*HEIGHT)
#define RAD     3
#define TILE    8
#define TXN     100         // 800/8
#define TYN     75          // 600/8
#define NTILES  (TXN*TYN)   // 7500
#define CAP     128         // center-binned slots/tile (hot mean ~49, +5 sigma ~84)
#define RCAP    256         // survivors per tile (empirical max ~230)

// 32B self-contained entry, stored as two 16B halves:
//   lo: {key (u64), xy|op<<32 (u64)}   hi: {r, g, b, 0} (float4)

// ---- fused: f64 extrinsics-inverse + projection + center-tile binning ----
__global__ void project_bin_kernel(const float* __restrict__ xyz,
                                   const float* __restrict__ opacity,
                                   const float* __restrict__ features,
                                   const float* __restrict__ K,
                                   const float* __restrict__ ext,
                                   int* __restrict__ tileCount,
                                   u64* __restrict__ entries, int N) {
    __shared__ double tinv[16];
    if (threadIdx.x == 0) {
        double A[4][8];
        for (int i = 0; i < 4; ++i)
            for (int j = 0; j < 4; ++j) { A[i][j] = (double)ext[i*4+j]; A[i][j+4] = (i == j) ? 1.0 : 0.0; }
        for (int c = 0; c < 4; ++c) {
            int p = c; double mx = fabs(A[c][c]);
            for (int r = c+1; r < 4; ++r) { double v = fabs(A[r][c]); if (v > mx) { mx = v; p = r; } }
            if (p != c) for (int j = 0; j < 8; ++j) { double t = A[c][j]; A[c][j] = A[p][j]; A[p][j] = t; }
            double piv = A[c][c];
            for (int j = 0; j < 8; ++j) A[c][j] /= piv;
            for (int r = 0; r < 4; ++r) {
                if (r == c) continue;
                double f = A[r][c];
                for (int j = 0; j < 8; ++j) A[r][j] -= f * A[c][j];
            }
        }
        for (int i = 0; i < 4; ++i)
            for (int j = 0; j < 4; ++j) tinv[i*4+j] = A[i][j+4];
    }
    __syncthreads();

    int i = blockIdx.x * blockDim.x + threadIdx.x;
    if (i >= N) return;

    // hoisted loads: depend only on i, overlap the f64 chain below
    float op = opacity[i];
    float fr = features[i*48+0], fg = features[i*48+1], fb = features[i*48+2];

    double x = (double)xyz[3*i], y = (double)xyz[3*i+1], z = (double)xyz[3*i+2];
    double cam[3];
#pragma unroll
    for (int j = 0; j < 3; ++j)
        cam[j] = x*tinv[4*j+0] + y*tinv[4*j+1] + z*tinv[4*j+2] + tinv[4*j+3];
    double s0 = cam[0]*(double)K[0] + cam[1]*(double)K[1] + cam[2]*(double)K[2];
    double s1 = cam[0]*(double)K[3] + cam[1]*(double)K[4] + cam[2]*(double)K[5];
    double s2 = cam[0]*(double)K[6] + cam[1]*(double)K[7] + cam[2]*(double)K[8];
    double px = s0 / s2, py = s1 / s2;
    double dep = cam[2];
    bool valid = (px >= 0.0) && (px < (double)WIDTH) && (py >= 0.0) && (py < (double)HEIGHT) && (dep > 0.0);
    if (!valid) return;                         // invalid points are never referenced
    int xi = (int)px, yi = (int)py;             // trunc == floor for px,py >= 0

    unsigned db = __float_as_uint((float)dep);  // depth > 0 -> bits monotonic
    u64 key  = ((u64)(~db) << 32) | (unsigned)i;                       // depth desc, idx asc
    u64 xyop = (u64)(unsigned)(xi | (yi << 16)) | ((u64)__float_as_uint(op) << 32);

    int t = (yi >> 3) * TXN + (xi >> 3);        // center tile only: ONE scattered line-touch
    int pos = atomicAdd(&tileCount[t << 4], 1); // padded counter (1 per 64B line)
    if (pos < CAP) {
        size_t slot = (size_t)t * CAP + pos;
        ulonglong2* e2 = (ulonglong2*)entries;
        e2[slot*2]   = make_ulonglong2(key, xyop);
        float4 hi = make_float4(fr, fg, fb, 0.f);
        e2[slot*2+1] = *(ulonglong2*)&hi;       // both halves in one aligned 64B... 32B region
    }
}

// ---- render: 9-neighbor candidate scan -> filter -> compact -> rank sort -> mask blend ----
__global__ __launch_bounds__(256, 8) void render_kernel(
        const int* __restrict__ tileCount,
        const u64* __restrict__ entries,
        float* __restrict__ out) {
    __shared__ alignas(16) u64 kbuf[RCAP];
    __shared__ int2   s_cxyop[RCAP];   // survivor (xy, op bits) by compaction slot
    __shared__ int    s_src[RCAP];     // survivor entry slot (for rgb fetch)
    __shared__ int    s_cnt;
    __shared__ u64    s_mask[RCAP];    // pixel coverage mask, by rank
    __shared__ float  s_w[49];
    __shared__ int2   s_eop[RCAP];     // (eterm, op bits), by rank
    __shared__ float4 s_rgbd[RCAP];    // (r,g,b,depth), by rank
    __shared__ float4 r_c[256];        // T,Sr,Sg,Sb
    __shared__ float2 r_ad[256];       // A,D

    int tile = blockIdx.x;
    int tid  = threadIdx.x;
    int lane = tid & 63, wid = tid >> 6;
    int txT = tile % TXN, tyT = tile / TXN;
    int tx0 = txT * TILE, ty0 = tyT * TILE;

    // 9 neighbor tiles: counts (broadcast loads) + register prefix sum (fully unrolled)
    int nb[9], pre[10];
    pre[0] = 0;
#pragma unroll
    for (int q = 0; q < 9; ++q) {
        int nx = txT + (q % 3) - 1, ny = tyT + (q / 3) - 1;
        bool ok = ((unsigned)nx < TXN) && ((unsigned)ny < TYN);
        int t = ok ? ny * TXN + nx : 0;
        nb[q] = t;
        int c = ok ? min(tileCount[t << 4], CAP) : 0;
        pre[q+1] = pre[q] + c;
    }
    int total = pre[9];

    if (tid == 0) s_cnt = 0;
    kbuf[tid] = ~0ull;                 // pad: never < any real key
    if (tid < 49) {
        int dx = tid % 7 - 3, dy = tid / 7 - 3;
        s_w[tid] = (float)exp(-0.5 * (double)(dx*dx + dy*dy));
    }
    __syncthreads();

    // candidate scan: load lo half, filter by apron, compact survivors
    const ulonglong2* e2 = (const ulonglong2*)entries;
    for (int c = tid; c < total; c += 256) {
        int src = 0;
#pragma unroll
        for (int q = 0; q < 9; ++q)
            if (c >= pre[q] && c < pre[q+1]) src = nb[q] * CAP + (c - pre[q]);
        ulonglong2 lo = e2[(size_t)src * 2];
        int xy  = (int)(unsigned)(lo.y & 0xFFFFFFFFull);
        int dxc = (xy & 0xFFFF) - tx0;
        int dyc = (xy >> 16)    - ty0;
        if ((unsigned)(dxc + RAD) <= 13u && (unsigned)(dyc + RAD) <= 13u) {
            int pos = atomicAdd(&s_cnt, 1);
            if (pos < RCAP) {
                kbuf[pos]    = lo.x;
                s_cxyop[pos] = make_int2(xy, (int)(lo.y >> 32));
                s_src[pos]   = src;
            }
        }
    }
    __syncthreads();
    int cnt = min(s_cnt, RCAP);

    // rank-sort survivors via paired LDS broadcast scan; gather rgb overlapped
    if (tid < cnt) {
        u64 key = kbuf[tid];
        int2 xo = s_cxyop[tid];
        float4 hi = *(const float4*)(e2 + (size_t)s_src[tid] * 2 + 1);  // rgb gather
        float dep = __uint_as_float(~(unsigned)(key >> 32));

        int rank = 0;
        int cr2 = (cnt + 1) & ~1;      // pad slot makes the pair read exact
        const ulonglong2* kb2 = (const ulonglong2*)kbuf;
        for (int j = 0; j < cr2; j += 2) {         // b128 broadcast: 2 keys/read
            ulonglong2 kk = kb2[j >> 1];
            rank += (kk.x < key) + (kk.y < key);
        }
        // coverage mask + additive weight-index term
        int dxc = (xo.x & 0xFFFF) - tx0;
        int dyc = (xo.x >> 16)    - ty0;
        int sx = dxc - 3, sy = dyc - 3;
        unsigned rm = (sx >= 0) ? ((0x7Fu << sx) & 0xFFu) : (0x7Fu >> (-sx));
        unsigned ym = (sy >= 0) ? ((0x7Fu << sy) & 0xFFu) : (0x7Fu >> (-sy));
        u64 msk = 0;
#pragma unroll
        for (int r = 0; r < 8; ++r)
            msk |= (u64)((ym >> r) & 1u ? rm : 0u) << (8 * r);
        s_mask[rank] = msk;
        s_eop[rank]  = make_int2((3 - dyc) * 7 + (3 - dxc), xo.y);
        s_rgbd[rank] = make_float4(hi.x, hi.y, hi.z, dep);
    }
    __syncthreads();

    // each wave blends one contiguous depth segment (over-op is associative)
    int seg = (cnt + 3) >> 2;           // <= 64 since cnt <= 256
    int sA = wid * seg, sB = min(sA + seg, cnt);
    int m = sB - sA; if (m < 0) m = 0;
    int laneterm = (lane >> 3) * 7 + (lane & 7);

    float T = 1.f, Sr = 0.f, Sg = 0.f, Sb = 0.f, Aa = 0.f, Dm = 0.f;
    for (int k2 = 0; k2 < m; ++k2) {
        int q = sA + k2;
        u64 msk = s_mask[q];                        // broadcast read
        if ((msk >> lane) & 1ull) {
            int2 eo = s_eop[q];
            float4 cd = s_rgbd[q];
            float w  = s_w[laneterm + eo.x];
            float a  = __int_as_float(eo.y) * w;
            float ia = 1.f - a;
            Sr = Sr * ia + cd.x * a;
            Sg = Sg * ia + cd.y * a;
            Sb = Sb * ia + cd.z * a;
            T *= ia;
            Aa = Aa + a * (1.f - Aa);
            float d = cd.w;
            Dm = (Dm == 0.f || d < Dm) ? d : Dm;
        }
    }

    r_c[tid]  = make_float4(T, Sr, Sg, Sb);
    r_ad[tid] = make_float2(Aa, Dm);
    __syncthreads();

    if (wid == 0) {   // compose 4 segments farthest->nearest, write all 5 planes
        float cr = 0.f, cg = 0.f, cb = 0.f, al = 0.f, dm = 0.f;
#pragma unroll
        for (int w = 0; w < 4; ++w) {
            int q = w * 64 + lane;
            float4 c = r_c[q];
            float2 ad = r_ad[q];
            cr = cr * c.x + c.y;
            cg = cg * c.x + c.z;
            cb = cb * c.x + c.w;
            al = al + ad.x * (1.f - al);
            float d = ad.y;
            if (d != 0.f && (dm == 0.f || d < dm)) dm = d;
        }
        int px = tx0 + (lane & 7);
        int py = ty0 + (lane >> 3);
        int pix = py * WIDTH + px;
        out[pix]          = cr;
        out[HWPX + pix]   = cg;
        out[2*HWPX + pix] = cb;
        out[3*HWPX + pix] = dm;
        out[4*HWPX + pix] = al;
    }
}

// ---------------- host launch ----------------
extern "C" void kernel_launch(void* const* d_in, const int* in_sizes, int n_in,
                              void* d_out, int out_size, void* d_ws, size_t ws_size,
                              hipStream_t stream) {
    const float* xyz      = (const float*)d_in[0];
    const float* opacity  = (const float*)d_in[3];
    const float* features = (const float*)d_in[4];
    const float* K        = (const float*)d_in[5];
    const float* ext      = (const float*)d_in[6];
    int N = in_sizes[0] / 3;

    char* ws = (char*)d_ws;
    size_t off = 0;
    int* tileCount = (int*)(ws + off);
    off += (size_t)NTILES * 16 * sizeof(int);          // 480 KB: one counter per 64B line
    off = (off + 127) & ~(size_t)127;
    u64* entries = (u64*)(ws + off);
    off += (size_t)NTILES * CAP * 32;                  // 30.7 MB: 32B entries

    hipMemsetAsync(tileCount, 0, (size_t)NTILES * 16 * sizeof(int), stream);
    int blocks = (N + 255) / 256;
    project_bin_kernel<<<blocks, 256, 0, stream>>>(xyz, opacity, features, K, ext,
                                                   tileCount, entries, N);
    render_kernel<<<NTILES, 256, 0, stream>>>(tileCount, entries, (float*)d_out);
}